// Round 7
// baseline (243.885 us; speedup 1.0000x reference)
//
#include <hip/hip_runtime.h>
#include <hip/hip_cooperative_groups.h>

namespace cg = cooperative_groups;

// Radius search (L2^2), single segment, M=4096 queries x N=8192 points.
// Out (float32, concat): [0,MN) packed idx (pad -1) | [MN,MN+M+1) row splits |
//                        [MN+M+1, 2MN+M+1) packed d2 (pad 0).
// Exact numpy fp32 op order (NO fma):
//   q2=(qx*qx+qy*qy)+qz*qz ; p2=(px*px+py*py)+pz*pz ; qp=(qx*px+qy*py)+qz*pz
//   d2=max((q2+p2)-2*qp, 0) ; mask: d2<=r*r  (max irrelevant for mask, r2>0)
//
// Primary path: ONE cooperative kernel (512 blocks x 256 thr):
//   phase1: count (2 q/wave, shared point loads, ballot masks->ws) + pad fill
//   grid.sync()
//   phase2: per-block redundant LDS scan of counts (block 0 emits splits)
//   phase3: mask-based pack of idx+dist
// Fallback (if coop launch unavailable): R6 two-kernel path.

typedef float f32x4 __attribute__((ext_vector_type(4)));

__device__ __forceinline__ void fill_region(float* __restrict__ base, long long n,
                                            float val, long long tid, long long nth) {
    long long head = (long long)(((16u - ((unsigned)(size_t)base & 15u)) & 15u) >> 2);
    if (head > n) head = n;
    for (long long i = tid; i < head; i += nth) base[i] = val;
    long long nv = (n - head) >> 2;
    f32x4* v = (f32x4*)(base + head);
    f32x4 vv = {val, val, val, val};
    for (long long i = tid; i < nv; i += nth) v[i] = vv;
    for (long long i = head + (nv << 2) + tid; i < n; i += nth) base[i] = val;
}

// ================= cooperative single-kernel path =================
__global__ __launch_bounds__(256, 2) void rs_coop(
    const float* __restrict__ pts, const float* __restrict__ qs,
    const float* __restrict__ rad, int* __restrict__ counts,
    unsigned long long* __restrict__ masks, float* __restrict__ out,
    long long MN, int N, int M) {
    cg::grid_group grid = cg::this_grid();
    const int t = threadIdx.x, bid = blockIdx.x;
    const int wv = t >> 6, lane = t & 63;
    const int nb = gridDim.x;
    const int gw = bid * 4 + wv, nwaves = nb * 4;
    const int nc = N >> 6;

    float* out_idx = out;
    float* out_splits = out + MN;
    float* out_dist = out + MN + M + 1;

    // ---- phase 1a: count, 2 queries per wave, shared point loads ----
    for (int q0 = gw * 2; q0 < M; q0 += nwaves * 2) {
        float qx[2], qy[2], qz[2], q2[2], r2[2];
#pragma unroll
        for (int j = 0; j < 2; ++j) {
            int q = q0 + j;
            bool v = (q < M);
            int qc = v ? q : (M - 1);
            float x = qs[3 * qc], y = qs[3 * qc + 1], z = qs[3 * qc + 2];
            qx[j] = x; qy[j] = y; qz[j] = z;
            q2[j] = __fadd_rn(__fadd_rn(__fmul_rn(x, x), __fmul_rn(y, y)), __fmul_rn(z, z));
            float r = rad[qc];
            r2[j] = v ? __fmul_rn(r, r) : -1.0f;  // raw d2 > -1 always
        }
        int cnt[2] = {0, 0};
#pragma unroll 2
        for (int c = 0; c < nc; ++c) {
            int p = (c << 6) + lane;
            float px = pts[3 * p], py = pts[3 * p + 1], pz = pts[3 * p + 2];
            float p2 = __fadd_rn(__fadd_rn(__fmul_rn(px, px), __fmul_rn(py, py)),
                                 __fmul_rn(pz, pz));
#pragma unroll
            for (int j = 0; j < 2; ++j) {
                float qp = __fadd_rn(__fadd_rn(__fmul_rn(qx[j], px), __fmul_rn(qy[j], py)),
                                     __fmul_rn(qz[j], pz));
                float d2 = __fsub_rn(__fadd_rn(q2[j], p2), __fmul_rn(2.0f, qp));
                unsigned long long b = __ballot(d2 <= r2[j]);
                if (lane == 0 && q0 + j < M) masks[(long long)(q0 + j) * nc + c] = b;
                cnt[j] += __popcll(b);
            }
        }
        if (lane == 0) {
#pragma unroll
            for (int j = 0; j < 2; ++j)
                if (q0 + j < M) counts[q0 + j] = cnt[j];
        }
    }

    // ---- phase 1b: pad fill (both regions, grid-strided) ----
    {
        long long tid = (long long)bid * 256 + t;
        long long nth = (long long)nb * 256;
        fill_region(out_idx, MN, -1.0f, tid, nth);
        fill_region(out_dist, MN, 0.0f, tid, nth);
    }

    __threadfence();
    grid.sync();

    // ---- phase 2: per-block redundant scan of counts -> s_split ----
    __shared__ int s_scan[256];
    __shared__ int s_split[4097];  // M <= 4096
    {
        int c[16];
        int sum = 0;
        int b16 = t * 16;
#pragma unroll
        for (int i = 0; i < 16; ++i) {
            int idx = b16 + i;
            int v = (idx < M) ? counts[idx] : 0;
            c[i] = sum;
            sum += v;
        }
        s_scan[t] = sum;
        __syncthreads();
        for (int off = 1; off < 256; off <<= 1) {
            int add = (t >= off) ? s_scan[t - off] : 0;
            __syncthreads();
            s_scan[t] += add;
            __syncthreads();
        }
        int excl = (t == 0) ? 0 : s_scan[t - 1];
#pragma unroll
        for (int i = 0; i < 16; ++i)
            if (b16 + i < M) s_split[b16 + i] = excl + c[i];
        if (t == 255) s_split[M] = excl + sum;
        __syncthreads();
    }
    if (bid == 0) {
        for (int i = t; i <= M; i += 256) out_splits[i] = (float)s_split[i];
    }

    // ---- phase 3: pack idx+dist from masks ----
    for (int q0 = gw * 2; q0 < M; q0 += nwaves * 2) {
#pragma unroll
        for (int j = 0; j < 2; ++j) {
            int w = q0 + j;
            if (w >= M) break;
            float qxx = qs[3 * w], qyy = qs[3 * w + 1], qzz = qs[3 * w + 2];
            float q2 = __fadd_rn(__fadd_rn(__fmul_rn(qxx, qxx), __fmul_rn(qyy, qyy)),
                                 __fmul_rn(qzz, qzz));
            long long base = s_split[w];
            const unsigned long long* mq = masks + (long long)w * nc;
            unsigned long long w0 = (lane < nc) ? mq[lane] : 0ull;
            unsigned long long w1 = (lane + 64 < nc) ? mq[lane + 64] : 0ull;
            int c0 = __popcll(w0), c1 = __popcll(w1);
            int i0 = c0, i1 = c1;
            for (int off = 1; off < 64; off <<= 1) {
                int t0 = __shfl_up(i0, off, 64);
                int t1 = __shfl_up(i1, off, 64);
                if (lane >= off) { i0 += t0; i1 += t1; }
            }
            int total0 = __shfl(i0, 63, 64);

            long long o = base + (i0 - c0);
            int pbase = lane << 6;
            unsigned long long mm = w0;
            while (mm) {
                int b = __ffsll((long long)mm) - 1;
                int p = pbase + b;
                float px = pts[3 * p], py = pts[3 * p + 1], pz = pts[3 * p + 2];
                float p2 = __fadd_rn(__fadd_rn(__fmul_rn(px, px), __fmul_rn(py, py)),
                                     __fmul_rn(pz, pz));
                float qp = __fadd_rn(__fadd_rn(__fmul_rn(qxx, px), __fmul_rn(qyy, py)),
                                     __fmul_rn(qzz, pz));
                float d2 = fmaxf(__fsub_rn(__fadd_rn(q2, p2), __fmul_rn(2.0f, qp)), 0.0f);
                out_idx[o] = (float)p;
                out_dist[o] = d2;
                ++o;
                mm &= mm - 1;
            }
            o = base + total0 + (i1 - c1);
            pbase = (lane + 64) << 6;
            mm = w1;
            while (mm) {
                int b = __ffsll((long long)mm) - 1;
                int p = pbase + b;
                float px = pts[3 * p], py = pts[3 * p + 1], pz = pts[3 * p + 2];
                float p2 = __fadd_rn(__fadd_rn(__fmul_rn(px, px), __fmul_rn(py, py)),
                                     __fmul_rn(pz, pz));
                float qp = __fadd_rn(__fadd_rn(__fmul_rn(qxx, px), __fmul_rn(qyy, py)),
                                     __fmul_rn(qzz, pz));
                float d2 = fmaxf(__fsub_rn(__fadd_rn(q2, p2), __fmul_rn(2.0f, qp)), 0.0f);
                out_idx[o] = (float)p;
                out_dist[o] = d2;
                ++o;
                mm &= mm - 1;
            }
        }
    }
}

// ================= fallback two-kernel path (R6, verified) =================
__global__ void rs_main(const float* __restrict__ pts, const float* __restrict__ qs,
                        const float* __restrict__ rad,
                        int* __restrict__ counts, unsigned long long* __restrict__ masks,
                        int storeMasks,
                        float* __restrict__ out, long long MN, int N, int M,
                        int countBlocks, int fillPerRegion) {
    int bid = blockIdx.x;
    if (bid < countBlocks) {
        int t = threadIdx.x;
        int wv = t >> 6, lane = t & 63;
        int q0 = (bid * 4 + wv) * 4;
        if (q0 >= M) return;
        float qx[4], qy[4], qz[4], q2[4], r2[4];
#pragma unroll
        for (int j = 0; j < 4; ++j) {
            int q = q0 + j;
            bool v = (q < M);
            int qc = v ? q : (M - 1);
            float x = qs[3 * qc], y = qs[3 * qc + 1], z = qs[3 * qc + 2];
            qx[j] = x; qy[j] = y; qz[j] = z;
            q2[j] = __fadd_rn(__fadd_rn(__fmul_rn(x, x), __fmul_rn(y, y)), __fmul_rn(z, z));
            float r = rad[qc];
            r2[j] = v ? __fmul_rn(r, r) : -1.0f;
        }
        int cnt[4] = {0, 0, 0, 0};
        int nc = N >> 6;
        unsigned long long* mq = masks + (long long)q0 * (long long)nc;
#pragma unroll 2
        for (int c = 0; c < nc; ++c) {
            int p = (c << 6) + lane;
            float px = pts[3 * p], py = pts[3 * p + 1], pz = pts[3 * p + 2];
            float p2 = __fadd_rn(__fadd_rn(__fmul_rn(px, px), __fmul_rn(py, py)),
                                 __fmul_rn(pz, pz));
            unsigned long long b[4];
#pragma unroll
            for (int j = 0; j < 4; ++j) {
                float qp = __fadd_rn(__fadd_rn(__fmul_rn(qx[j], px), __fmul_rn(qy[j], py)),
                                     __fmul_rn(qz[j], pz));
                float d2 = __fsub_rn(__fadd_rn(q2[j], p2), __fmul_rn(2.0f, qp));
                b[j] = __ballot(d2 <= r2[j]);
                cnt[j] += __popcll(b[j]);
            }
            if (storeMasks && lane == 0) {
#pragma unroll
                for (int j = 0; j < 4; ++j)
                    if (q0 + j < M) mq[(long long)j * nc + c] = b[j];
            }
        }
        if (lane == 0) {
#pragma unroll
            for (int j = 0; j < 4; ++j)
                if (q0 + j < M) counts[q0 + j] = cnt[j];
        }
    } else {
        int fb = bid - countBlocks;
        long long start;
        float val;
        int fb0;
        if (fb < fillPerRegion) { start = 0; val = -1.0f; fb0 = fb; }
        else { start = MN + (long long)M + 1; val = 0.0f; fb0 = fb - fillPerRegion; }
        long long tid = (long long)fb0 * blockDim.x + threadIdx.x;
        long long nth = (long long)fillPerRegion * blockDim.x;
        fill_region(out + start, MN, val, tid, nth);
    }
}

__global__ __launch_bounds__(1024) void rs_write(
    const float* __restrict__ pts, const float* __restrict__ qs,
    const float* __restrict__ rad,
    const int* __restrict__ counts, const unsigned long long* __restrict__ masks,
    float* __restrict__ out_idx, float* __restrict__ out_splits,
    float* __restrict__ out_dist, int N, int M) {
    __shared__ int s_scan[1024];
    __shared__ int s_split[4097];
    int t = threadIdx.x;
    int c[4];
    int sum = 0;
    int base4 = t * 4;
#pragma unroll
    for (int i = 0; i < 4; ++i) {
        int v = (base4 + i < M) ? counts[base4 + i] : 0;
        c[i] = sum;
        sum += v;
    }
    s_scan[t] = sum;
    __syncthreads();
    for (int off = 1; off < 1024; off <<= 1) {
        int add = (t >= off) ? s_scan[t - off] : 0;
        __syncthreads();
        s_scan[t] += add;
        __syncthreads();
    }
    int excl = (t == 0) ? 0 : s_scan[t - 1];
#pragma unroll
    for (int i = 0; i < 4; ++i)
        if (base4 + i < M) s_split[base4 + i] = excl + c[i];
    if (t == 1023) s_split[M] = excl + sum;
    __syncthreads();
    if (blockIdx.x == 0) {
        for (int i = t; i <= M; i += 1024) out_splits[i] = (float)s_split[i];
    }
    int wv = t >> 6, lane = t & 63;
    int w = blockIdx.x * 16 + wv;
    if (w >= M) return;
    float qxx = qs[3 * w], qyy = qs[3 * w + 1], qzz = qs[3 * w + 2];
    float q2 = __fadd_rn(__fadd_rn(__fmul_rn(qxx, qxx), __fmul_rn(qyy, qyy)),
                         __fmul_rn(qzz, qzz));
    long long base = s_split[w];
    int nw = N >> 6;
    const unsigned long long* mq = masks + (long long)w * nw;
    unsigned long long w0 = (lane < nw) ? mq[lane] : 0ull;
    unsigned long long w1 = (lane + 64 < nw) ? mq[lane + 64] : 0ull;
    int c0 = __popcll(w0), c1 = __popcll(w1);
    int i0 = c0, i1 = c1;
    for (int off = 1; off < 64; off <<= 1) {
        int t0 = __shfl_up(i0, off, 64);
        int t1 = __shfl_up(i1, off, 64);
        if (lane >= off) { i0 += t0; i1 += t1; }
    }
    int total0 = __shfl(i0, 63, 64);
    long long o = base + (i0 - c0);
    int pbase = lane << 6;
    unsigned long long mm = w0;
    while (mm) {
        int b = __ffsll((long long)mm) - 1;
        int p = pbase + b;
        float px = pts[3 * p], py = pts[3 * p + 1], pz = pts[3 * p + 2];
        float p2 = __fadd_rn(__fadd_rn(__fmul_rn(px, px), __fmul_rn(py, py)),
                             __fmul_rn(pz, pz));
        float qp = __fadd_rn(__fadd_rn(__fmul_rn(qxx, px), __fmul_rn(qyy, py)),
                             __fmul_rn(qzz, pz));
        float d2 = fmaxf(__fsub_rn(__fadd_rn(q2, p2), __fmul_rn(2.0f, qp)), 0.0f);
        out_idx[o] = (float)p;
        out_dist[o] = d2;
        ++o;
        mm &= mm - 1;
    }
    o = base + total0 + (i1 - c1);
    pbase = (lane + 64) << 6;
    mm = w1;
    while (mm) {
        int b = __ffsll((long long)mm) - 1;
        int p = pbase + b;
        float px = pts[3 * p], py = pts[3 * p + 1], pz = pts[3 * p + 2];
        float p2 = __fadd_rn(__fadd_rn(__fmul_rn(px, px), __fmul_rn(py, py)),
                             __fmul_rn(pz, pz));
        float qp = __fadd_rn(__fadd_rn(__fmul_rn(qxx, px), __fmul_rn(qyy, py)),
                             __fmul_rn(qzz, pz));
        float d2 = fmaxf(__fsub_rn(__fadd_rn(q2, p2), __fmul_rn(2.0f, qp)), 0.0f);
        out_idx[o] = (float)p;
        out_dist[o] = d2;
        ++o;
        mm &= mm - 1;
    }
}

extern "C" void kernel_launch(void* const* d_in, const int* in_sizes, int n_in,
                              void* d_out, int out_size, void* d_ws, size_t ws_size,
                              hipStream_t stream) {
    const float* points = (const float*)d_in[0];
    const float* queries = (const float*)d_in[1];
    const float* radii = (const float*)d_in[2];
    int N = in_sizes[0] / 3;
    int M = in_sizes[1] / 3;
    long long MN = (long long)M * (long long)N;

    float* out = (float*)d_out;
    float* out_idx = out;
    float* out_splits = out + MN;
    float* out_dist = out + MN + M + 1;

    // running-offset ws allocator (R2 lesson: never hand-sum offsets)
    char* ws = (char*)d_ws;
    size_t off = 0;
    auto take = [&](size_t bytes) -> size_t {
        size_t o = off;
        off += (bytes + 255) & ~(size_t)255;
        return o;
    };
    size_t o_counts = take((size_t)M * 4);
    size_t o_masks = take((size_t)M * (size_t)(N / 64) * 8);
    bool fits = (off <= ws_size);
    int* counts = (int*)(ws + o_counts);
    unsigned long long* masks = (unsigned long long*)(ws + o_masks);

    bool coopOK = fits && (M <= 4096) && (N % 64 == 0) && ((N >> 6) <= 128);
    if (coopOK) {
        void* args[] = {(void*)&points, (void*)&queries, (void*)&radii, (void*)&counts,
                        (void*)&masks,  (void*)&out,     (void*)&MN,    (void*)&N,
                        (void*)&M};
        hipError_t err = hipLaunchCooperativeKernel((const void*)rs_coop, dim3(512),
                                                    dim3(256), args, 0, stream);
        if (err == hipSuccess) return;
        (void)hipGetLastError();  // clear, fall through to fallback
    }

    // fallback: R6 two-kernel path (requires mask ws; fits is guaranteed in harness)
    int countBlocks = (M + 15) / 16;
    int fillPerRegion = 768;
    int grid = countBlocks + 2 * fillPerRegion;
    rs_main<<<grid, 256, 0, stream>>>(points, queries, radii, counts, masks, 1, out, MN,
                                      N, M, countBlocks, fillPerRegion);
    int writeBlocks = (M + 15) / 16;
    rs_write<<<writeBlocks, 1024, 0, stream>>>(points, queries, radii, counts, masks,
                                               out_idx, out_splits, out_dist, N, M);
}

// Round 8
// 86.278 us; speedup vs baseline: 2.8267x; 2.8267x over previous
//
#include <hip/hip_runtime.h>

// Radius search (L2^2), single segment, M=4096 queries x N=8192 points.
// Out (float32, concat): [0,MN) packed idx (pad -1) | [MN,MN+M+1) row splits |
//                        [MN+M+1, 2MN+M+1) packed d2 (pad 0).
// Exact numpy fp32 op order (NO fma):
//   q2=(qx*qx+qy*qy)+qz*qz ; p2=(px*px+py*py)+pz*pz ; qp=(qx*px+qy*py)+qz*pz
//   d2=max((q2+p2)-2*qp, 0) ; mask: d2<=r*r  (max irrelevant for mask, r2>0)
//
// R7 lesson (rocprof): coop single-kernel = 23.7% occupancy, serial phases,
// 1.1 TB/s -> 252us. Multi-kernel with full occupancy wins.
// R8: 2 kernels. K1 = count+fill with MODULO-INTERLEAVED roles (even bid =
// count, odd = fill) so every CU runs fill stores from t=0 with count hiding
// under them; 2048 blocks = 8/CU co-resident. K2 = cheap per-block redundant
// scan (256-wide ladder) + mask-based pack, block 0 emits splits.

typedef float f32x4 __attribute__((ext_vector_type(4)));

__device__ __forceinline__ void fill_region(float* __restrict__ base, long long n,
                                            float val, long long tid, long long nth) {
    long long head = (long long)(((16u - ((unsigned)(size_t)base & 15u)) & 15u) >> 2);
    if (head > n) head = n;
    for (long long i = tid; i < head; i += nth) base[i] = val;
    long long nv = (n - head) >> 2;
    f32x4* v = (f32x4*)(base + head);
    f32x4 vv = {val, val, val, val};
    for (long long i = tid; i < nv; i += nth) v[i] = vv;
    for (long long i = head + (nv << 2) + tid; i < n; i += nth) base[i] = val;
}

// ---------------- K1: interleaved count + pad-fill ----------------
__global__ __launch_bounds__(256) void rs_main(
    const float* __restrict__ pts, const float* __restrict__ qs,
    const float* __restrict__ rad, int* __restrict__ counts,
    unsigned long long* __restrict__ masks, int storeMasks,
    float* __restrict__ out, long long MN, int N, int M,
    int C /*count blocks*/, int F /*fill blocks*/) {
    int bid = blockIdx.x;
    int t = threadIdx.x;

    // role: even->count, odd->fill when C==F (harness shape); else range split
    int countId = -1, fillId = -1;
    if (C == F) {
        if ((bid & 1) == 0) countId = bid >> 1;
        else fillId = bid >> 1;
    } else {
        if (bid < C) countId = bid;
        else fillId = bid - C;
    }

    if (countId >= 0) {
        int wv = t >> 6, lane = t & 63;
        int w = countId * 4 + wv;  // one wave per query
        if (w >= M) return;
        float qx = qs[3 * w], qy = qs[3 * w + 1], qz = qs[3 * w + 2];
        float q2 = __fadd_rn(__fadd_rn(__fmul_rn(qx, qx), __fmul_rn(qy, qy)),
                             __fmul_rn(qz, qz));
        float r = rad[w];
        float r2 = __fmul_rn(r, r);
        int nc = N >> 6;
        unsigned long long* mq = masks + (long long)w * nc;
        int cnt = 0;
#pragma unroll 2
        for (int c = 0; c < nc; ++c) {
            int p = (c << 6) + lane;
            float px = pts[3 * p], py = pts[3 * p + 1], pz = pts[3 * p + 2];
            float p2 = __fadd_rn(__fadd_rn(__fmul_rn(px, px), __fmul_rn(py, py)),
                                 __fmul_rn(pz, pz));
            float qp = __fadd_rn(__fadd_rn(__fmul_rn(qx, px), __fmul_rn(qy, py)),
                                 __fmul_rn(qz, pz));
            float d2 = __fsub_rn(__fadd_rn(q2, p2), __fmul_rn(2.0f, qp));
            unsigned long long b = __ballot(d2 <= r2);
            if (storeMasks && lane == 0) mq[c] = b;
            cnt += __popcll(b);
        }
        if (lane == 0) counts[w] = cnt;
    } else {
        int half = F >> 1;
        long long start;
        float val;
        int fb0;
        if (fillId < half) { start = 0; val = -1.0f; fb0 = fillId; }
        else { start = MN + (long long)M + 1; val = 0.0f; fb0 = fillId - half; }
        long long tid = (long long)fb0 * blockDim.x + t;
        long long nth = (long long)half * blockDim.x;
        fill_region(out + start, MN, val, tid, nth);
    }
}

// ---------------- K2: redundant cheap scan + mask pack ----------------
__global__ __launch_bounds__(256) void rs_write(
    const float* __restrict__ pts, const float* __restrict__ qs,
    const float* __restrict__ rad,
    const int* __restrict__ counts, const unsigned long long* __restrict__ masks,
    int useMasks,
    float* __restrict__ out_idx, float* __restrict__ out_splits,
    float* __restrict__ out_dist, int N, int M) {
    __shared__ int s_scan[256];
    __shared__ int s_split[4097];  // M <= 4096
    int t = threadIdx.x;

    // per-block exclusive scan of counts[M]: 16 per thread + 256 ladder
    {
        int c[16];
        int sum = 0;
        int b16 = t * 16;
#pragma unroll
        for (int i = 0; i < 16; ++i) {
            int idx = b16 + i;
            int v = (idx < M) ? counts[idx] : 0;
            c[i] = sum;
            sum += v;
        }
        s_scan[t] = sum;
        __syncthreads();
        for (int off = 1; off < 256; off <<= 1) {
            int add = (t >= off) ? s_scan[t - off] : 0;
            __syncthreads();
            s_scan[t] += add;
            __syncthreads();
        }
        int excl = (t == 0) ? 0 : s_scan[t - 1];
#pragma unroll
        for (int i = 0; i < 16; ++i)
            if (b16 + i < M) s_split[b16 + i] = excl + c[i];
        if (t == 255) s_split[M] = excl + sum;
        __syncthreads();
    }

    if (blockIdx.x == 0) {
        for (int i = t; i <= M; i += 256) out_splits[i] = (float)s_split[i];
    }

    int wv = t >> 6, lane = t & 63;
    int w = blockIdx.x * 4 + wv;  // one wave per query
    if (w >= M) return;
    float qxx = qs[3 * w], qyy = qs[3 * w + 1], qzz = qs[3 * w + 2];
    float q2 = __fadd_rn(__fadd_rn(__fmul_rn(qxx, qxx), __fmul_rn(qyy, qyy)),
                         __fmul_rn(qzz, qzz));
    long long base = s_split[w];
    int nc = N >> 6;

    if (useMasks) {
        const unsigned long long* mq = masks + (long long)w * nc;
        unsigned long long w0 = (lane < nc) ? mq[lane] : 0ull;
        unsigned long long w1 = (lane + 64 < nc) ? mq[lane + 64] : 0ull;
        int c0 = __popcll(w0), c1 = __popcll(w1);
        int i0 = c0, i1 = c1;
        for (int off = 1; off < 64; off <<= 1) {
            int t0 = __shfl_up(i0, off, 64);
            int t1 = __shfl_up(i1, off, 64);
            if (lane >= off) { i0 += t0; i1 += t1; }
        }
        int total0 = __shfl(i0, 63, 64);

        long long o = base + (i0 - c0);
        int pbase = lane << 6;
        unsigned long long mm = w0;
        while (mm) {
            int b = __ffsll((long long)mm) - 1;
            int p = pbase + b;
            float px = pts[3 * p], py = pts[3 * p + 1], pz = pts[3 * p + 2];
            float p2 = __fadd_rn(__fadd_rn(__fmul_rn(px, px), __fmul_rn(py, py)),
                                 __fmul_rn(pz, pz));
            float qp = __fadd_rn(__fadd_rn(__fmul_rn(qxx, px), __fmul_rn(qyy, py)),
                                 __fmul_rn(qzz, pz));
            float d2 = fmaxf(__fsub_rn(__fadd_rn(q2, p2), __fmul_rn(2.0f, qp)), 0.0f);
            out_idx[o] = (float)p;
            out_dist[o] = d2;
            ++o;
            mm &= mm - 1;
        }
        o = base + total0 + (i1 - c1);
        pbase = (lane + 64) << 6;
        mm = w1;
        while (mm) {
            int b = __ffsll((long long)mm) - 1;
            int p = pbase + b;
            float px = pts[3 * p], py = pts[3 * p + 1], pz = pts[3 * p + 2];
            float p2 = __fadd_rn(__fadd_rn(__fmul_rn(px, px), __fmul_rn(py, py)),
                                 __fmul_rn(pz, pz));
            float qp = __fadd_rn(__fadd_rn(__fmul_rn(qxx, px), __fmul_rn(qyy, py)),
                                 __fmul_rn(qzz, pz));
            float d2 = fmaxf(__fsub_rn(__fadd_rn(q2, p2), __fmul_rn(2.0f, qp)), 0.0f);
            out_idx[o] = (float)p;
            out_dist[o] = d2;
            ++o;
            mm &= mm - 1;
        }
    } else {
        // fallback: recompute + ballot pack (only if masks don't fit in ws)
        float r = rad[w];
        float r2 = __fmul_rn(r, r);
        int cum = 0;
        unsigned long long lanemask = (1ull << lane) - 1ull;
        for (int p0 = 0; p0 < N; p0 += 64) {
            int p = p0 + lane;
            float px = pts[3 * p], py = pts[3 * p + 1], pz = pts[3 * p + 2];
            float p2 = __fadd_rn(__fadd_rn(__fmul_rn(px, px), __fmul_rn(py, py)),
                                 __fmul_rn(pz, pz));
            float qp = __fadd_rn(__fadd_rn(__fmul_rn(qxx, px), __fmul_rn(qyy, py)),
                                 __fmul_rn(qzz, pz));
            float d2 = __fsub_rn(__fadd_rn(q2, p2), __fmul_rn(2.0f, qp));
            bool pred = (d2 <= r2);
            unsigned long long mask = __ballot(pred);
            if (pred) {
                long long pos = base + cum + __popcll(mask & lanemask);
                out_idx[pos] = (float)p;
                out_dist[pos] = fmaxf(d2, 0.0f);
            }
            cum += __popcll(mask);
        }
    }
}

extern "C" void kernel_launch(void* const* d_in, const int* in_sizes, int n_in,
                              void* d_out, int out_size, void* d_ws, size_t ws_size,
                              hipStream_t stream) {
    const float* points = (const float*)d_in[0];
    const float* queries = (const float*)d_in[1];
    const float* radii = (const float*)d_in[2];
    int N = in_sizes[0] / 3;
    int M = in_sizes[1] / 3;
    long long MN = (long long)M * (long long)N;

    float* out = (float*)d_out;
    float* out_idx = out;
    float* out_splits = out + MN;
    float* out_dist = out + MN + M + 1;

    // running-offset ws allocator (R2 lesson: never hand-sum offsets)
    char* ws = (char*)d_ws;
    size_t off = 0;
    auto take = [&](size_t bytes) -> size_t {
        size_t o = off;
        off += (bytes + 255) & ~(size_t)255;
        return o;
    };
    size_t o_counts = take((size_t)M * 4);
    size_t o_masks = take((size_t)M * (size_t)(N / 64) * 8);
    bool useMasks = (off <= ws_size) && ((N >> 6) <= 128);  // pack path needs nc<=128
    int* counts = (int*)(ws + o_counts);
    unsigned long long* masks = (unsigned long long*)(ws + o_masks);

    int C = (M + 3) / 4;   // count blocks: 4 waves/block, 1 query/wave
    int F = 1024;          // fill blocks: 512 per region
    rs_main<<<C + F, 256, 0, stream>>>(points, queries, radii, counts, masks,
                                       useMasks ? 1 : 0, out, MN, N, M, C, F);
    int writeBlocks = (M + 3) / 4;  // 4 queries (waves) per 256-thr block
    rs_write<<<writeBlocks, 256, 0, stream>>>(points, queries, radii, counts, masks,
                                              useMasks ? 1 : 0, out_idx, out_splits,
                                              out_dist, N, M);
}